// Round 3
// baseline (185.457 us; speedup 1.0000x reference)
//
#include <hip/hip_runtime.h>
#include <math.h>

#define NN 20000   // nodes
#define NE 40000   // edges
#define H 64
#define F_ATOM 62
#define F_BOND 6
#define NB 512     // graphs

typedef __bf16 bf16x8 __attribute__((ext_vector_type(8)));
typedef float f32x16 __attribute__((ext_vector_type(16)));

__device__ __forceinline__ float selu_f(float x) {
    const float scale = 1.0507009873554805f;
    const float alpha = 1.6732632423543772f;
    return scale * (x > 0.0f ? x : alpha * (__expf(x) - 1.0f));
}

// Fused prep: ew_prep | pad_h | edge_mlp | zero msg | zero gsum
// ranges: [0,32768) ewprep, [32768,1312768) pad, [1312768,3872768) mlp,
//         [3872768,4192768) msg zero (float4), [4192768,4200960) gsum zero (float4)
__global__ void prep_kernel(const float* __restrict__ nf, const float* __restrict__ ef,
                            const float* __restrict__ Wm, const float* __restrict__ bm,
                            const float* __restrict__ Ew,
                            float* __restrict__ h, float* __restrict__ mlp,
                            __bf16* __restrict__ ewb, float* __restrict__ msg,
                            float* __restrict__ gsum) {
    int gid = blockIdx.x * 256 + threadIdx.x;
    if (gid < 32768) {
        // Ew (f32 [64][4096]) -> bf16 B-fragment-linear for mfma_f32_32x32x16_bf16
        int tid = gid;
        int l = tid & 63;
        int nt = (tid >> 6) & 1;
        int c = tid >> 7;                              // 0..255 = kk*4 + q
        int kk = c >> 2;
        int jbase = (c & 3) * 16 + (l >> 5) * 8;
        int i = nt * 32 + (l & 31);
        const float* src = Ew + kk * 4096 + i * 64 + jbase;
        __bf16* dst = ewb + tid * 8;
#pragma unroll
        for (int t = 0; t < 8; ++t) dst[t] = (__bf16)src[t];
    } else if (gid < 1312768) {
        int idx = gid - 32768;
        int n = idx >> 6, c = idx & 63;
        h[idx] = (c < F_ATOM) ? nf[n * F_ATOM + c] : 0.0f;
    } else if (gid < 3872768) {
        int t = gid - 1312768;
        int e = t >> 6, i = t & 63;
        const float* efe = ef + e * F_BOND;
        float s = bm[i];
#pragma unroll
        for (int j = 0; j < F_BOND; ++j) s = fmaf(efe[j], Wm[j * H + i], s);
        mlp[t] = fmaxf(s, 0.0f);
    } else if (gid < 4192768) {
        int idx = gid - 3872768;
        reinterpret_cast<float4*>(msg)[idx] = make_float4(0.f, 0.f, 0.f, 0.f);
    } else if (gid < 4200960) {
        int idx = gid - 4192768;
        reinterpret_cast<float4*>(gsum)[idx] = make_float4(0.f, 0.f, 0.f, 0.f);
    }
}

// em[e,i] = sum_{kk,j} mlp[e,kk]*hj[e,j]*Ew[kk,i*64+j]; atomicAdd into msg[ed[e]]
// Block: 320 threads (5 waves), 160 edges, K-split 4 (16 kk per block).
// Wave w owns edges [w*32, w*32+32); per s-iter stage 1 kk slice (8 KB) of Ew.
__global__ __launch_bounds__(320, 4) void edge_message_mfma(
    const float* __restrict__ h, const float* __restrict__ mlp,
    const int* __restrict__ ed, const int* __restrict__ er,
    const __bf16* __restrict__ ewb, float* __restrict__ msg)
{
    __shared__ float mlpT_s[16][161];     // [kk_local][e_local]
    __shared__ bf16x8 ewbuf[2][512];      // double-buffered 1-kk Ew slice (8 KB each)
    __shared__ int edom_s[160];

    const int t = threadIdx.x;
    const int w = t >> 6;                 // 0..4
    const int lane = t & 63;
    const int l31 = lane & 31;
    const int hf = lane >> 5;
    const int bid = blockIdx.x;
    const int eb = (bid >> 2) * 160;      // edge base
    const int k0 = (bid & 3) * 16;        // kk base (K-split 4)

    if (t < 160) edom_s[t] = ed[eb + t];

    // stage mlp[eb+e][k0..k0+16) transposed: thread t -> e = t>>1, part = t&1 (8 kk)
    {
        int e = t >> 1, part = t & 1;
        const float* mp = mlp + (eb + e) * H + k0 + part * 8;
        float4 v0 = *reinterpret_cast<const float4*>(mp);
        float4 v1 = *reinterpret_cast<const float4*>(mp + 4);
        int r = part * 8;
        mlpT_s[r + 0][e] = v0.x; mlpT_s[r + 1][e] = v0.y;
        mlpT_s[r + 2][e] = v0.z; mlpT_s[r + 3][e] = v0.w;
        mlpT_s[r + 4][e] = v1.x; mlpT_s[r + 5][e] = v1.y;
        mlpT_s[r + 6][e] = v1.z; mlpT_s[r + 7][e] = v1.w;
    }

    // per-lane hj: edge = eb + w*32 + l31, j = q*16 + hf*8 + tt
    const int eloc = w * 32 + l31;
    const int hrow = er[eb + eloc];
    float hjr[32];
    {
        const float* hp = h + hrow * H + hf * 8;
#pragma unroll
        for (int q = 0; q < 4; ++q) {
            float4 v0 = *reinterpret_cast<const float4*>(hp + q * 16);
            float4 v1 = *reinterpret_cast<const float4*>(hp + q * 16 + 4);
            hjr[q * 8 + 0] = v0.x; hjr[q * 8 + 1] = v0.y;
            hjr[q * 8 + 2] = v0.z; hjr[q * 8 + 3] = v0.w;
            hjr[q * 8 + 4] = v1.x; hjr[q * 8 + 5] = v1.y;
            hjr[q * 8 + 6] = v1.z; hjr[q * 8 + 7] = v1.w;
        }
    }

    // stage the 8 KB slice for kk: waves 0-3 load 2 KB each (2 x 1 KB)
    auto stage = [&](int kk, int buf) {
        if (w < 4) {
            const __bf16* gs = ewb + kk * 4096 + w * 1024 + lane * 8;
            char* lb = reinterpret_cast<char*>(&ewbuf[buf][0]) + w * 2048 + lane * 16;
#pragma unroll
            for (int r = 0; r < 2; ++r) {
                __builtin_amdgcn_global_load_lds(
                    (const __attribute__((address_space(1))) void*)(gs + r * 512),
                    (__attribute__((address_space(3))) void*)(lb + r * 1024),
                    16, 0, 0);
            }
        }
    };

    f32x16 acc0, acc1;
#pragma unroll
    for (int i = 0; i < 16; ++i) { acc0[i] = 0.0f; acc1[i] = 0.0f; }

    stage(k0, 0);
    asm volatile("s_waitcnt vmcnt(0)" ::: "memory");
    __syncthreads();

    int cur = 0;
    for (int s = 0; s < 16; ++s) {
        if (s < 15) stage(k0 + s + 1, cur ^ 1);
        float mval = mlpT_s[s][w * 32 + l31];
#pragma unroll
        for (int q = 0; q < 4; ++q) {
            bf16x8 a;
#pragma unroll
            for (int tt = 0; tt < 8; ++tt) a[tt] = (__bf16)(mval * hjr[q * 8 + tt]);
            bf16x8 b0 = ewbuf[cur][(q * 2 + 0) * 64 + lane];
            bf16x8 b1 = ewbuf[cur][(q * 2 + 1) * 64 + lane];
            acc0 = __builtin_amdgcn_mfma_f32_32x32x16_bf16(a, b0, acc0, 0, 0, 0);
            acc1 = __builtin_amdgcn_mfma_f32_32x32x16_bf16(a, b1, acc1, 0, 0, 0);
        }
        asm volatile("s_waitcnt vmcnt(0)" ::: "memory");
        __syncthreads();
        cur ^= 1;
    }

    // C/D layout: col = lane&31, row = (r&3) + 8*(r>>2) + 4*(lane>>5)
#pragma unroll
    for (int r = 0; r < 16; ++r) {
        const int m = (r & 3) + 8 * (r >> 2) + 4 * hf;
        const int dom = edom_s[w * 32 + m];
        atomicAdd(&msg[dom * H + l31], acc0[r]);
        atomicAdd(&msg[dom * H + 32 + l31], acc1[r]);
    }
}

// h[n,i] = selu(msg[n] @ Wu + bu[i] + h[n,i]); zeroes msg after read (4 nodes/block)
__global__ void node_update_kernel(float* __restrict__ msg, const float* __restrict__ Wu,
                                   const float* __restrict__ bu, float* __restrict__ h) {
    __shared__ float ms[4][68];
    int t = threadIdx.x;
    int nb = blockIdx.x * 4;
    int ln = t >> 6, i = t & 63;
    int o = (nb + ln) * H + i;
    ms[ln][i] = msg[o];
    msg[o] = 0.0f;                       // ready for next edge_message / replay
    __syncthreads();
    float s = bu[i];
#pragma unroll
    for (int k = 0; k < H; ++k) s = fmaf(ms[ln][k], Wu[k * H + i], s);
    h[o] = selu_f(s + h[o]);
}

// fused: ae = h@Wae+bae; aa = selu(ae@WR+bR); atomicAdd gsum[gid[n]] (4 nodes/block)
__global__ void embed_readout_kernel(const float* __restrict__ h, const float* __restrict__ Wae,
                                     const float* __restrict__ bae, const float* __restrict__ WR,
                                     const float* __restrict__ bR, const int* __restrict__ gid,
                                     float* __restrict__ gsum) {
    __shared__ float hs[4][68];
    __shared__ float as_[4][68];
    int t = threadIdx.x;
    int nb = blockIdx.x * 4;
    int ln = t >> 6, i = t & 63;
    hs[ln][i] = h[(nb + ln) * H + i];
    __syncthreads();
    float s = bae[i];
#pragma unroll
    for (int k = 0; k < H; ++k) s = fmaf(hs[ln][k], Wae[k * H + i], s);
    as_[ln][i] = s;
    __syncthreads();
    float s2 = bR[i];
#pragma unroll
    for (int k = 0; k < H; ++k) s2 = fmaf(as_[ln][k], WR[k * H + i], s2);
    atomicAdd(&gsum[gid[nb + ln] * H + i], selu_f(s2));
}

// per graph: ge = tanh(gsum); mo = relu(ge @ Wmlp + bmlp); out = mo @ Wout + bout
__global__ void final_kernel(const float* __restrict__ gsum, const float* __restrict__ Wmlp,
                             const float* __restrict__ bmlp, const float* __restrict__ Wout,
                             const float* __restrict__ bout, float* __restrict__ out) {
    __shared__ float ge[64];
    int g = blockIdx.x, i = threadIdx.x;
    ge[i] = tanhf(gsum[g * H + i]);
    __syncthreads();
    float s = bmlp[i];
#pragma unroll
    for (int k = 0; k < H; ++k) s = fmaf(ge[k], Wmlp[k * H + i], s);
    float mo = fmaxf(s, 0.0f) * Wout[i];
#pragma unroll
    for (int off = 32; off > 0; off >>= 1) mo += __shfl_down(mo, off);
    if (i == 0) out[g] = mo + bout[0];
}

extern "C" void kernel_launch(void* const* d_in, const int* in_sizes, int n_in,
                              void* d_out, int out_size, void* d_ws, size_t ws_size,
                              hipStream_t stream) {
    const float* nf   = (const float*)d_in[0];
    const float* ef   = (const float*)d_in[1];
    const int*   ed   = (const int*)d_in[2];   // edge_domain (scatter dest)
    const int*   er   = (const int*)d_in[3];   // edge_range  (gather src)
    const int*   gid  = (const int*)d_in[4];
    const float* Wm   = (const float*)d_in[5];
    const float* bm   = (const float*)d_in[6];
    const float* Ew   = (const float*)d_in[7];
    const float* Wu0  = (const float*)d_in[8];
    const float* bu0  = (const float*)d_in[9];
    const float* Wu1  = (const float*)d_in[10];
    const float* bu1  = (const float*)d_in[11];
    const float* Wae  = (const float*)d_in[12];
    const float* bae  = (const float*)d_in[13];
    const float* WR   = (const float*)d_in[14];
    const float* bR   = (const float*)d_in[15];
    const float* Wmlp = (const float*)d_in[16];
    const float* bmlp = (const float*)d_in[17];
    const float* Wout = (const float*)d_in[18];
    const float* bout = (const float*)d_in[19];
    float* out = (float*)d_out;

    float* ws   = (float*)d_ws;
    float* h    = ws;                                   // 20000*64
    float* mlp  = ws + 1280000;                         // 40000*64
    float* msg  = ws + 1280000 + 2560000;               // 20000*64
    float* gsum = msg + 1280000;                        // 512*64
    __bf16* ewb = (__bf16*)(gsum + 32768);              // 262144 bf16

    prep_kernel<<<16410, 256, 0, stream>>>(nf, ef, Wm, bm, Ew, h, mlp, ewb, msg, gsum);

    for (int stepi = 0; stepi < 2; ++stepi) {
        edge_message_mfma<<<(NE / 160) * 4, 320, 0, stream>>>(h, mlp, ed, er, ewb, msg);
        node_update_kernel<<<NN / 4, 256, 0, stream>>>(msg, stepi ? Wu1 : Wu0,
                                                       stepi ? bu1 : bu0, h);
    }

    embed_readout_kernel<<<NN / 4, 256, 0, stream>>>(h, Wae, bae, WR, bR, gid, gsum);
    final_kernel<<<NB, 64, 0, stream>>>(gsum, Wmlp, bmlp, Wout, bout, out);
}

// Round 5
// 164.041 us; speedup vs baseline: 1.1306x; 1.1306x over previous
//
#include <hip/hip_runtime.h>
#include <math.h>

#define NN 20000   // nodes
#define NE 40000   // edges
#define H 64
#define F_ATOM 62
#define F_BOND 6
#define NB 512     // graphs

typedef __bf16 bf16x8 __attribute__((ext_vector_type(8)));
typedef float f32x16 __attribute__((ext_vector_type(16)));

__device__ __forceinline__ float selu_f(float x) {
    const float scale = 1.0507009873554805f;
    const float alpha = 1.6732632423543772f;
    return scale * (x > 0.0f ? x : alpha * (__expf(x) - 1.0f));
}

// Fused prep: ew_prep | pad_h | edge_mlp | zero msg | zero gsum   (round-3 verbatim, PASSED)
__global__ void prep_kernel(const float* __restrict__ nf, const float* __restrict__ ef,
                            const float* __restrict__ Wm, const float* __restrict__ bm,
                            const float* __restrict__ Ew,
                            float* __restrict__ h, float* __restrict__ mlp,
                            __bf16* __restrict__ ewb, float* __restrict__ msg,
                            float* __restrict__ gsum) {
    int gid = blockIdx.x * 256 + threadIdx.x;
    if (gid < 32768) {
        // Ew (f32 [64][4096]) -> bf16 B-fragment-linear for mfma_f32_32x32x16_bf16
        int tid = gid;
        int l = tid & 63;
        int nt = (tid >> 6) & 1;
        int c = tid >> 7;                              // 0..255 = kk*4 + q
        int kk = c >> 2;
        int jbase = (c & 3) * 16 + (l >> 5) * 8;
        int i = nt * 32 + (l & 31);
        const float* src = Ew + kk * 4096 + i * 64 + jbase;
        __bf16* dst = ewb + tid * 8;
#pragma unroll
        for (int t = 0; t < 8; ++t) dst[t] = (__bf16)src[t];
    } else if (gid < 1312768) {
        int idx = gid - 32768;
        int n = idx >> 6, c = idx & 63;
        h[idx] = (c < F_ATOM) ? nf[n * F_ATOM + c] : 0.0f;
    } else if (gid < 3872768) {
        int t = gid - 1312768;
        int e = t >> 6, i = t & 63;
        const float* efe = ef + e * F_BOND;
        float s = bm[i];
#pragma unroll
        for (int j = 0; j < F_BOND; ++j) s = fmaf(efe[j], Wm[j * H + i], s);
        mlp[t] = fmaxf(s, 0.0f);
    } else if (gid < 4192768) {
        int idx = gid - 3872768;
        reinterpret_cast<float4*>(msg)[idx] = make_float4(0.f, 0.f, 0.f, 0.f);
    } else if (gid < 4200960) {
        int idx = gid - 4192768;
        reinterpret_cast<float4*>(gsum)[idx] = make_float4(0.f, 0.f, 0.f, 0.f);
    }
}

// em[e,i] = sum_{kk,j} mlp[e,kk]*hj[e,j]*Ew[kk,i*64+j]; atomicAdd into msg[ed[e]]
// Block: 320 threads (5 waves), 160 edges, FULL K (64 kk).
// Wave w owns edges [w*32, w*32+32). Slice = 2 kk (16 KB bf16), double-buffered,
// staged by waves 0-3 via global_load_lds (round-3-proven split).
// Inner loop body is round-2-verbatim (passed, absmax 9.8e-4).
__global__ __launch_bounds__(320) void edge_message_mfma(
    const float* __restrict__ h, const float* __restrict__ mlp,
    const int* __restrict__ ed, const int* __restrict__ er,
    const __bf16* __restrict__ ewb, float* __restrict__ msg)
{
    __shared__ __bf16 mlpT_s[64][168];    // [kk][e_local], 21 KB
    __shared__ bf16x8 ewbuf[2][1024];     // 2 x 16 KB slices (2 kk each)
    __shared__ int edom_s[160];

    const int t = threadIdx.x;
    const int w = t >> 6;                 // 0..4
    const int lane = t & 63;
    const int l31 = lane & 31;
    const int hf = lane >> 5;
    const int eb = blockIdx.x * 160;

    if (t < 160) edom_s[t] = ed[eb + t];

    // stage mlp transposed: t -> e = t>>1 (0..159), part = t&1 (32 kk each)
    {
        int e = t >> 1, part = t & 1;
        const float* mp = mlp + (size_t)(eb + e) * H + part * 32;
#pragma unroll
        for (int c4 = 0; c4 < 8; ++c4) {
            float4 v = reinterpret_cast<const float4*>(mp)[c4];
            int k = part * 32 + c4 * 4;
            mlpT_s[k + 0][e] = (__bf16)v.x;
            mlpT_s[k + 1][e] = (__bf16)v.y;
            mlpT_s[k + 2][e] = (__bf16)v.z;
            mlpT_s[k + 3][e] = (__bf16)v.w;
        }
    }

    // per-lane hj: edge = eb + w*32 + l31, j = q*16 + hf*8 + tt   (round-2 verbatim)
    const int e0 = w * 32;
    const int hrow = er[eb + e0 + l31];
    float hjr[32];
    {
        const float* hp = h + hrow * H + hf * 8;
#pragma unroll
        for (int q = 0; q < 4; ++q) {
            float4 v0 = *reinterpret_cast<const float4*>(hp + q * 16);
            float4 v1 = *reinterpret_cast<const float4*>(hp + q * 16 + 4);
            hjr[q * 8 + 0] = v0.x; hjr[q * 8 + 1] = v0.y;
            hjr[q * 8 + 2] = v0.z; hjr[q * 8 + 3] = v0.w;
            hjr[q * 8 + 4] = v1.x; hjr[q * 8 + 5] = v1.y;
            hjr[q * 8 + 6] = v1.z; hjr[q * 8 + 7] = v1.w;
        }
    }

    // stage 16 KB slice s (kk = 2s, 2s+1): waves 0-3 load 4 KB each
    auto stage = [&](int s, int buf) {
        if (w < 4) {
            const char* gs = reinterpret_cast<const char*>(ewb) + (size_t)s * 16384 + w * 4096 + lane * 16;
            char* lb = reinterpret_cast<char*>(&ewbuf[buf][0]) + w * 4096 + lane * 16;
#pragma unroll
            for (int r = 0; r < 4; ++r) {
                __builtin_amdgcn_global_load_lds(
                    (const __attribute__((address_space(1))) void*)(gs + r * 1024),
                    (__attribute__((address_space(3))) void*)(lb + r * 1024),
                    16, 0, 0);
            }
        }
    };

    f32x16 acc0, acc1;
#pragma unroll
    for (int i = 0; i < 16; ++i) { acc0[i] = 0.0f; acc1[i] = 0.0f; }

    stage(0, 0);
    asm volatile("s_waitcnt vmcnt(0)" ::: "memory");
    __syncthreads();

    int cur = 0;
    for (int s = 0; s < 32; ++s) {
        if (s < 31) stage(s + 1, cur ^ 1);
#pragma unroll
        for (int cc = 0; cc < 8; ++cc) {
            const int kk = s * 2 + (cc >> 2);
            const int q = cc & 3;
            float mval = (float)mlpT_s[kk][e0 + l31];
            bf16x8 a;
#pragma unroll
            for (int tt = 0; tt < 8; ++tt) a[tt] = (__bf16)(mval * hjr[q * 8 + tt]);
            bf16x8 b0 = ewbuf[cur][(cc * 2 + 0) * 64 + lane];
            bf16x8 b1 = ewbuf[cur][(cc * 2 + 1) * 64 + lane];
            acc0 = __builtin_amdgcn_mfma_f32_32x32x16_bf16(a, b0, acc0, 0, 0, 0);
            acc1 = __builtin_amdgcn_mfma_f32_32x32x16_bf16(a, b1, acc1, 0, 0, 0);
        }
        asm volatile("s_waitcnt vmcnt(0)" ::: "memory");
        __syncthreads();
        cur ^= 1;
    }

    // C/D layout: col = lane&31, row = (r&3) + 8*(r>>2) + 4*(lane>>5)   (round-2 verbatim)
#pragma unroll
    for (int r = 0; r < 16; ++r) {
        const int m = (r & 3) + 8 * (r >> 2) + 4 * hf;
        const int dom = edom_s[e0 + m];
        atomicAdd(&msg[dom * H + l31], acc0[r]);
        atomicAdd(&msg[dom * H + 32 + l31], acc1[r]);
    }
}

// h[n,i] = selu(msg[n] @ Wu + bu[i] + h[n,i]); zeroes msg after read (round-3 verbatim)
__global__ void node_update_kernel(float* __restrict__ msg, const float* __restrict__ Wu,
                                   const float* __restrict__ bu, float* __restrict__ h) {
    __shared__ float ms[4][68];
    int t = threadIdx.x;
    int nb = blockIdx.x * 4;
    int ln = t >> 6, i = t & 63;
    int o = (nb + ln) * H + i;
    ms[ln][i] = msg[o];
    msg[o] = 0.0f;                       // ready for next edge_message / replay
    __syncthreads();
    float s = bu[i];
#pragma unroll
    for (int k = 0; k < H; ++k) s = fmaf(ms[ln][k], Wu[k * H + i], s);
    h[o] = selu_f(s + h[o]);
}

// fused: ae = h@Wae+bae; aa = selu(ae@WR+bR); atomicAdd gsum[gid[n]]   (round-3 verbatim)
__global__ void embed_readout_kernel(const float* __restrict__ h, const float* __restrict__ Wae,
                                     const float* __restrict__ bae, const float* __restrict__ WR,
                                     const float* __restrict__ bR, const int* __restrict__ gid,
                                     float* __restrict__ gsum) {
    __shared__ float hs[4][68];
    __shared__ float as_[4][68];
    int t = threadIdx.x;
    int nb = blockIdx.x * 4;
    int ln = t >> 6, i = t & 63;
    hs[ln][i] = h[(nb + ln) * H + i];
    __syncthreads();
    float s = bae[i];
#pragma unroll
    for (int k = 0; k < H; ++k) s = fmaf(hs[ln][k], Wae[k * H + i], s);
    as_[ln][i] = s;
    __syncthreads();
    float s2 = bR[i];
#pragma unroll
    for (int k = 0; k < H; ++k) s2 = fmaf(as_[ln][k], WR[k * H + i], s2);
    atomicAdd(&gsum[gid[nb + ln] * H + i], selu_f(s2));
}

// per graph: ge = tanh(gsum); mo = relu(ge @ Wmlp + bmlp); out = mo @ Wout + bout (round-1 verbatim)
__global__ void final_kernel(const float* __restrict__ gsum, const float* __restrict__ Wmlp,
                             const float* __restrict__ bmlp, const float* __restrict__ Wout,
                             const float* __restrict__ bout, float* __restrict__ out) {
    __shared__ float ge[64];
    int g = blockIdx.x, i = threadIdx.x;
    ge[i] = tanhf(gsum[g * H + i]);
    __syncthreads();
    float s = bmlp[i];
#pragma unroll
    for (int k = 0; k < H; ++k) s = fmaf(ge[k], Wmlp[k * H + i], s);
    float mo = fmaxf(s, 0.0f) * Wout[i];
#pragma unroll
    for (int off = 32; off > 0; off >>= 1) mo += __shfl_down(mo, off);
    if (i == 0) out[g] = mo + bout[0];
}

extern "C" void kernel_launch(void* const* d_in, const int* in_sizes, int n_in,
                              void* d_out, int out_size, void* d_ws, size_t ws_size,
                              hipStream_t stream) {
    const float* nf   = (const float*)d_in[0];
    const float* ef   = (const float*)d_in[1];
    const int*   ed   = (const int*)d_in[2];   // edge_domain (scatter dest)
    const int*   er   = (const int*)d_in[3];   // edge_range  (gather src)
    const int*   gid  = (const int*)d_in[4];
    const float* Wm   = (const float*)d_in[5];
    const float* bm   = (const float*)d_in[6];
    const float* Ew   = (const float*)d_in[7];
    const float* Wu0  = (const float*)d_in[8];
    const float* bu0  = (const float*)d_in[9];
    const float* Wu1  = (const float*)d_in[10];
    const float* bu1  = (const float*)d_in[11];
    const float* Wae  = (const float*)d_in[12];
    const float* bae  = (const float*)d_in[13];
    const float* WR   = (const float*)d_in[14];
    const float* bR   = (const float*)d_in[15];
    const float* Wmlp = (const float*)d_in[16];
    const float* bmlp = (const float*)d_in[17];
    const float* Wout = (const float*)d_in[18];
    const float* bout = (const float*)d_in[19];
    float* out = (float*)d_out;

    float* ws   = (float*)d_ws;
    float* h    = ws;                                   // 20000*64
    float* mlp  = ws + 1280000;                         // 40000*64
    float* msg  = ws + 1280000 + 2560000;               // 20000*64
    float* gsum = msg + 1280000;                        // 512*64
    __bf16* ewb = (__bf16*)(gsum + 32768);              // 262144 bf16

    prep_kernel<<<16410, 256, 0, stream>>>(nf, ef, Wm, bm, Ew, h, mlp, ewb, msg, gsum);

    for (int stepi = 0; stepi < 2; ++stepi) {
        edge_message_mfma<<<NE / 160, 320, 0, stream>>>(h, mlp, ed, er, ewb, msg);
        node_update_kernel<<<NN / 4, 256, 0, stream>>>(msg, stepi ? Wu1 : Wu0,
                                                       stepi ? bu1 : bu0, h);
    }

    embed_readout_kernel<<<NN / 4, 256, 0, stream>>>(h, Wae, bae, WR, bR, gid, gsum);
    final_kernel<<<NB, 64, 0, stream>>>(gsum, Wmlp, bmlp, Wout, bout, out);
}